// Round 15
// baseline (279.920 us; speedup 1.0000x reference)
//
#include <hip/hip_runtime.h>

// x: [16, 512, 64, 64] fp32, memory: [1024, 512] fp32
// recon: [16, 512, 64, 64] fp32, match: [16, 64, 64] fp32
#define C_DIM 512
#define K_MEM 1024

typedef __attribute__((ext_vector_type(8))) short short8;     // 8 bf16
typedef __attribute__((ext_vector_type(4))) float f32x4;
typedef __attribute__((ext_vector_type(16))) float f32x16;
typedef __attribute__((ext_vector_type(4))) unsigned int u32x4;

#define LGKM0()  asm volatile("s_waitcnt lgkmcnt(0)" ::: "memory")
#define VM0()    asm volatile("s_waitcnt vmcnt(0)" ::: "memory")
#define BAR()    { asm volatile("" ::: "memory"); __builtin_amdgcn_s_barrier(); asm volatile("" ::: "memory"); }

// unsinkable 16B global load (fused-fallback path)
#define GLOAD16(dst, addr, imm) \
    asm volatile("global_load_dwordx4 %0, %1, off offset:%c2" \
                 : "=v"(dst) : "v"(addr), "n"(imm))
#define WAITV(N) do { asm volatile("s_waitcnt vmcnt(%c0)" :: "n"(N) : "memory"); \
                      __builtin_amdgcn_sched_barrier(0); } while (0)

__device__ __forceinline__ unsigned short f2bf(float f) {
    unsigned int u = __builtin_bit_cast(unsigned int, f);
    unsigned int r = (u + 0x7fffu + ((u >> 16) & 1u)) >> 16;  // RNE
    return (unsigned short)r;
}

__device__ __forceinline__ f32x4 mfma16(short8 a, short8 b, f32x4 c) {
    return __builtin_amdgcn_mfma_f32_16x16x32_bf16(a, b, c, 0, 0, 0);
}
__device__ __forceinline__ f32x16 mfma32(short8 a, short8 b, f32x16 c) {
    return __builtin_amdgcn_mfma_f32_32x32x16_bf16(a, b, c, 0, 0, 0);
}

__device__ __forceinline__ void gl_lds16(const void* g, void* l) {
    __builtin_amdgcn_global_load_lds(
        (const __attribute__((address_space(1))) unsigned int*)g,
        (__attribute__((address_space(3))) unsigned int*)l, 16, 0, 0);
}

// ---------------- prep 1: L2-normalize memory rows -> bf16 Mn[k][c] ----------------
__global__ __launch_bounds__(256)
void prep_norm(const float* __restrict__ mem, unsigned short* __restrict__ Mn) {
    int k = blockIdx.x, t = threadIdx.x;
    const float* row = mem + (size_t)k * C_DIM;
    float2 v = *reinterpret_cast<const float2*>(row + 2 * t);
    float ss = v.x * v.x + v.y * v.y;
#pragma unroll
    for (int off = 32; off >= 1; off >>= 1) ss += __shfl_xor(ss, off);
    __shared__ float wp[4];
    if ((t & 63) == 0) wp[t >> 6] = ss;
    __syncthreads();
    float tot = wp[0] + wp[1] + wp[2] + wp[3];
    float rn = 1.0f / fmaxf(sqrtf(tot), 1e-12f);
    unsigned int pk = (unsigned int)f2bf(v.x * rn) | ((unsigned int)f2bf(v.y * rn) << 16);
    *reinterpret_cast<unsigned int*>(Mn + (size_t)k * C_DIM + 2 * t) = pk;
}

// ---------------- prep 2: transpose Mn[k][c] -> MnT[c][k] ----------------
__global__ __launch_bounds__(256)
void prep_transpose(const unsigned short* __restrict__ Mn, unsigned short* __restrict__ MnT) {
    __shared__ unsigned short tl[64][72];
    int t = threadIdx.x;
    int bk = blockIdx.x & 15, bc = blockIdx.x >> 4;
    int k0 = bk * 64, c0 = bc * 64;
    {
        int kr = t >> 2, gc = (t & 3) * 16;
        const u32x4* src = reinterpret_cast<const u32x4*>(Mn + (size_t)(k0 + kr) * C_DIM + c0 + gc);
        u32x4 a = src[0], b = src[1];
        *reinterpret_cast<u32x4*>(&tl[kr][gc]) = a;
        *reinterpret_cast<u32x4*>(&tl[kr][gc + 8]) = b;
    }
    __syncthreads();
    {
        int cr = t >> 2, gk = (t & 3) * 16;
        unsigned int ow[8];
#pragma unroll
        for (int j = 0; j < 8; ++j)
            ow[j] = (unsigned int)tl[gk + 2 * j][cr] | ((unsigned int)tl[gk + 2 * j + 1][cr] << 16);
        unsigned int* dst = reinterpret_cast<unsigned int*>(MnT + (size_t)(c0 + cr) * K_MEM + k0 + gk);
#pragma unroll
        for (int j = 0; j < 8; ++j) dst[j] = ow[j];
    }
}

// ---------------- normx: L2-normalize feature rows -> Fn[n][c] bf16 ----------------
__global__ __launch_bounds__(512)
void normx_kernel(const float* __restrict__ x, unsigned short* __restrict__ Fn) {
    __shared__ alignas(16) char FnB[65536];   // [64 rows][64 granules 16B], gs = g ^ (w&31)
    __shared__ float normpart[64][9];
    __shared__ float rnormS[64];
    const int t = threadIdx.x, bid = blockIdx.x;   // bid = b*64 + h
    const int b = bid >> 6, h = bid & 63;
    const int lane = t & 63, wv = t >> 6;
    const int w = lane, cg = wv;
    const float* xp = x + (size_t)b * 2097152 + (size_t)(cg * 64) * 4096 + (size_t)h * 64 + w;
    float xv[64];
#pragma unroll
    for (int i = 0; i < 64; ++i) xv[i] = xp[(size_t)i * 4096];
    float ss = 0.f;
#pragma unroll
    for (int i = 0; i < 64; ++i) ss += xv[i] * xv[i];
    normpart[w][cg] = ss;
    __syncthreads();
    if (t < 64) {
        float s = 0.f;
#pragma unroll
        for (int j = 0; j < 8; ++j) s += normpart[t][j];
        rnormS[t] = 1.0f / fmaxf(sqrtf(s), 1e-12f);
    }
    __syncthreads();
    float rn = rnormS[w];
    char* fnrow = FnB + w * 1024;
#pragma unroll
    for (int j = 0; j < 8; ++j) {
        u32x4 pk4;
#pragma unroll
        for (int p = 0; p < 4; ++p) {
            float v0 = xv[j * 8 + 2 * p] * rn;
            float v1 = xv[j * 8 + 2 * p + 1] * rn;
            pk4[p] = (unsigned int)f2bf(v0) | ((unsigned int)f2bf(v1) << 16);
        }
        int gs = (cg * 8 + j) ^ (w & 31);
        *(u32x4*)(fnrow + (gs << 4)) = pk4;
    }
    __syncthreads();
    const int r = t >> 3;
    char* orow = (char*)(Fn + (size_t)(bid * 64 + r) * C_DIM);
#pragma unroll
    for (int p = 0; p < 8; ++p) {
        int gl = p * 8 + (t & 7);
        u32x4 v = *(const u32x4*)(FnB + r * 1024 + ((gl ^ (r & 31)) << 4));
        *(u32x4*)(orow + gl * 16) = v;
    }
}

// ---------------- shared GEMM staging: 128 rows x 64 cols bf16, source-swizzled ----------------
// LDS linear [128][8 granules of 16B]; LDS[r][g] = G[r][col0 + (g^(r&7))*8 .. +8]. 4 waves.
__device__ __forceinline__ void stage_tile(const char* g0, size_t rowBytes, int col0,
                                           char* lds0, int wv, int lane) {
#pragma unroll
    for (int j = 0; j < 4; ++j) {
        const int chunk = wv * 4 + j;                 // 16 chunks of 8 rows
        const int r = chunk * 8 + (lane >> 3);
        const int gs = (lane & 7) ^ (r & 7);
        const char* src = g0 + (size_t)r * rowBytes + col0 + gs * 16;
        gl_lds16(src, lds0 + chunk * 1024);
    }
}

// frag read: row r (0..127), k-granule gk (0..7) -> 16B
#define FRAG(base, r, gk) (*(const short8*)((base) + (r) * 128 + ((((gk)) ^ ((r) & 7)) << 4)))

// 2-phase double-buffered K-loop (T3 minimum): stage(kt+1) issued BEFORE compute(kt);
// single VM0+BAR per tile AFTER the MFMAs (load latency hidden under compute).
// Buffer reuse safety: stage of iter kt+1 writes buf^1; the buffer it overwrites was
// last read in iter kt-1, and all those reads completed before that iter's barrier.
#define GEMM_KLOOP_DBUF(NKT, ABYT, BBYT)                                                 \
    stage_tile(Ag, ABYT, 0, LDSU, wv, lane);                                             \
    stage_tile(Bg, BBYT, 0, LDSU + 16384, wv, lane);                                     \
    VM0(); BAR();                                                                        \
    _Pragma("unroll 1")                                                                  \
    for (int kt = 0; kt < (NKT); ++kt) {                                                 \
        char* As = LDSU + (kt & 1) * 32768;                                              \
        char* Bs = As + 16384;                                                           \
        if (kt + 1 < (NKT)) {                                                            \
            char* nb = LDSU + ((kt + 1) & 1) * 32768;                                    \
            stage_tile(Ag, ABYT, (kt + 1) * 128, nb, wv, lane);                          \
            stage_tile(Bg, BBYT, (kt + 1) * 128, nb + 16384, wv, lane);                  \
        }                                                                                \
        _Pragma("unroll")                                                                \
        for (int ks = 0; ks < 2; ++ks) {                                                 \
            short8 af[4], bfr[4];                                                        \
            _Pragma("unroll")                                                            \
            for (int i = 0; i < 4; ++i) {                                                \
                af[i]  = FRAG(As, wm * 64 + i * 16 + l15, ks * 4 + l4);                  \
                bfr[i] = FRAG(Bs, wn * 64 + i * 16 + l15, ks * 4 + l4);                  \
            }                                                                            \
            _Pragma("unroll")                                                            \
            for (int mf = 0; mf < 4; ++mf)                                               \
                _Pragma("unroll")                                                        \
                for (int nf = 0; nf < 4; ++nf)                                           \
                    acc[mf][nf] = mfma16(af[mf], bfr[nf], acc[mf][nf]);                  \
        }                                                                                \
        if (kt + 1 < (NKT)) { VM0(); }                                                   \
        BAR();                                                                           \
    }

// ---------------- GEMM1: S = Fn . Mn^T, fused exp + row partials + P store ----------------
// M=65536, N=1024, K=512. Tile 128x128, BK=64 dbuf, 4 waves (2m x 2n). grid 4096.
__global__ __launch_bounds__(256)
void gemm1_kernel(const unsigned short* __restrict__ Fn, const unsigned short* __restrict__ Mn,
                  unsigned short* __restrict__ P, float* __restrict__ Zp, float* __restrict__ Mp) {
    __shared__ alignas(16) char LDSU[65536];          // dbuf As/Bs x2; epilogue: Pscr[128][272B]
    __shared__ float zS[128][2], zM[128][2];

    const int wg = (blockIdx.x & 7) * 512 + (blockIdx.x >> 3);  // XCD-chunked
    const int mt = wg >> 3, nt = wg & 7;
    const int m0 = mt * 128, n0 = nt * 128;
    const int t = threadIdx.x, lane = t & 63, wv = t >> 6;
    const int wm = wv >> 1, wn = wv & 1;
    const int l15 = lane & 15, l4 = lane >> 4;

    const char* Ag = (const char*)Fn + (size_t)m0 * 1024;
    const char* Bg = (const char*)Mn + (size_t)n0 * 1024;

    f32x4 acc[4][4];
#pragma unroll
    for (int i = 0; i < 4; ++i)
#pragma unroll
        for (int j = 0; j < 4; ++j) acc[i][j] = (f32x4){0.f, 0.f, 0.f, 0.f};

    GEMM_KLOOP_DBUF(8, 1024, 1024)

    // ---- epilogue: exp, row partials (sum & max of exp), P -> global via LDS transpose ----
    float zsum[4][4], zmax[4][4];
#pragma unroll
    for (int mf = 0; mf < 4; ++mf)
#pragma unroll
        for (int r = 0; r < 4; ++r) { zsum[mf][r] = 0.f; zmax[mf][r] = 0.f; }
#pragma unroll
    for (int mf = 0; mf < 4; ++mf)
#pragma unroll
        for (int nf = 0; nf < 4; ++nf)
#pragma unroll
            for (int r = 0; r < 4; ++r) {
                float e = __expf(acc[mf][nf][r]);
                acc[mf][nf][r] = e;                 // reuse acc as exp store
                zsum[mf][r] += e;
                zmax[mf][r] = fmaxf(zmax[mf][r], e);  // max(exp) = exp(max)
            }
#pragma unroll
    for (int off = 1; off < 16; off <<= 1)
#pragma unroll
        for (int mf = 0; mf < 4; ++mf)
#pragma unroll
            for (int r = 0; r < 4; ++r) {
                zsum[mf][r] += __shfl_xor(zsum[mf][r], off);
                zmax[mf][r] = fmaxf(zmax[mf][r], __shfl_xor(zmax[mf][r], off));
            }
    if (l15 == 0) {
#pragma unroll
        for (int mf = 0; mf < 4; ++mf)
#pragma unroll
            for (int r = 0; r < 4; ++r) {
                int row = wm * 64 + mf * 16 + l4 * 4 + r;
                zS[row][wn] = zsum[mf][r];
                zM[row][wn] = zmax[mf][r];
            }
    }
    // P tile -> Pscr (bf16, row stride 272B) ; safe: after final loop barrier
    char* Pscr = LDSU;
#pragma unroll
    for (int mf = 0; mf < 4; ++mf)
#pragma unroll
        for (int nf = 0; nf < 4; ++nf)
#pragma unroll
            for (int r = 0; r < 4; ++r) {
                int row = wm * 64 + mf * 16 + l4 * 4 + r;
                int col = wn * 64 + nf * 16 + l15;
                *(unsigned short*)(Pscr + row * 272 + col * 2) = f2bf(acc[mf][nf][r]);
            }
    LGKM0(); BAR();
    if (t < 128) {
        float zq = zS[t][0] + zS[t][1];
        float mq = fmaxf(zM[t][0], zM[t][1]);
        Zp[(size_t)(m0 + t) * 8 + nt] = zq;
        Mp[(size_t)(m0 + t) * 8 + nt] = mq;
    }
    // coalesced dump of P tile: 4 rows x 256B per wave-instr
#pragma unroll
    for (int p = 0; p < 8; ++p) {
        int r = (t >> 4) + p * 16;
        u32x4 v = *(const u32x4*)(Pscr + r * 272 + (t & 15) * 16);
        *(u32x4*)((char*)P + (size_t)(m0 + r) * 2048 + n0 * 2 + (t & 15) * 16) = v;
    }
}

// ---------------- GEMM2: recon = (P . MnT^T) * Zinv, stats fused, transposed store ----------------
// M=65536(pix), N=512(c), K=1024. Tile 128x128, BK=64 dbuf, 4 waves. grid 2048.
__global__ __launch_bounds__(256)
void gemm2_kernel(const unsigned short* __restrict__ P, const unsigned short* __restrict__ MnT,
                  const float* __restrict__ Zp, const float* __restrict__ Mp,
                  float* __restrict__ recon, float* __restrict__ match) {
    __shared__ alignas(16) char LDSU[65536];
    __shared__ float zinvS[128];

    const int wg = (blockIdx.x & 7) * 256 + (blockIdx.x >> 3);  // XCD-chunked
    const int mt = wg >> 2, nt = wg & 3;
    const int m0 = mt * 128, n0 = nt * 128;
    const int t = threadIdx.x, lane = t & 63, wv = t >> 6;
    const int wm = wv >> 1, wn = wv & 1;
    const int l15 = lane & 15, l4 = lane >> 4;

    // fused stats: reduce the 8 per-ntile partials; ntile-0 blocks also write match
    if (t < 128) {
        f32x4 a = *(const f32x4*)(Zp + (size_t)(m0 + t) * 8);
        f32x4 b = *(const f32x4*)(Zp + (size_t)(m0 + t) * 8 + 4);
        float s = (a[0] + a[1] + a[2] + a[3]) + (b[0] + b[1] + b[2] + b[3]);
        float zi = 1.0f / s;
        zinvS[t] = zi;
        if (nt == 0) {
            f32x4 c = *(const f32x4*)(Mp + (size_t)(m0 + t) * 8);
            f32x4 d = *(const f32x4*)(Mp + (size_t)(m0 + t) * 8 + 4);
            float m = fmaxf(fmaxf(fmaxf(c[0], c[1]), fmaxf(c[2], c[3])),
                            fmaxf(fmaxf(d[0], d[1]), fmaxf(d[2], d[3])));
            match[m0 + t] = m * zi;
        }
    }

    const char* Ag = (const char*)P + (size_t)m0 * 2048;
    const char* Bg = (const char*)MnT + (size_t)n0 * 2048;

    f32x4 acc[4][4];
#pragma unroll
    for (int i = 0; i < 4; ++i)
#pragma unroll
        for (int j = 0; j < 4; ++j) acc[i][j] = (f32x4){0.f, 0.f, 0.f, 0.f};

    GEMM_KLOOP_DBUF(16, 2048, 2048)

    // ---- epilogue: scale by Zinv[pix], store recon[b][c][pix] (f32x4 over pix) ----
    const int b = m0 >> 12;
    const int inb0 = m0 & 4095;
#pragma unroll
    for (int mf = 0; mf < 4; ++mf) {
        f32x4 zv = *(const f32x4*)(&zinvS[wm * 64 + mf * 16 + l4 * 4]);
#pragma unroll
        for (int nf = 0; nf < 4; ++nf) {
            f32x4 v = acc[mf][nf];
            v[0] *= zv[0]; v[1] *= zv[1]; v[2] *= zv[2]; v[3] *= zv[3];
            int c = n0 + wn * 64 + nf * 16 + l15;
            int inb = inb0 + wm * 64 + mf * 16 + l4 * 4;
            *(f32x4*)(recon + (size_t)b * 2097152 + (size_t)c * 4096 + inb) = v;
        }
    }
}

// ---------------- fused fallback (round-6 kernel, used when ws is small) ----------------
__global__ __launch_bounds__(512)
__attribute__((amdgpu_waves_per_eu(2, 2)))
void fused_attn(const float* __restrict__ x,
                const unsigned short* __restrict__ Mn,
                const unsigned short* __restrict__ MnT,
                float* __restrict__ recon,
                float* __restrict__ match) {
    __shared__ alignas(16) char FnB[65536];
    __shared__ alignas(16) char PldsB[2 * 32768];
    __shared__ float Zinv[64], rnormS[64];

    const int t = threadIdx.x;
    const int bid = blockIdx.x;
    const int b = bid >> 6, h = bid & 63;
    const int lane = t & 63, wv = t >> 6;
    const int l31 = lane & 31, l5 = lane >> 5;
    const int ko = wv;
    const int cb = wv * 64;

    {
        float* normpart = (float*)PldsB;
        const int w = lane, cg = wv;
        const float* xp = x + (size_t)b * 2097152 + (size_t)(cg * 64) * 4096 + (size_t)h * 64 + w;
        float xv[64];
#pragma unroll
        for (int i = 0; i < 64; ++i) xv[i] = xp[(size_t)i * 4096];
        float ss = 0.f;
#pragma unroll
        for (int i = 0; i < 64; ++i) ss += xv[i] * xv[i];
        normpart[w * 9 + cg] = ss;
        __syncthreads();
        if (t < 64) {
            float s = 0.f;
#pragma unroll
            for (int j = 0; j < 8; ++j) s += normpart[t * 9 + j];
            rnormS[t] = 1.0f / fmaxf(sqrtf(s), 1e-12f);
        }
        __syncthreads();
        float rn = rnormS[w];
        char* fnrow = FnB + w * 1024;
#pragma unroll
        for (int j = 0; j < 8; ++j) {
            u32x4 pk4;
#pragma unroll
            for (int p = 0; p < 4; ++p) {
                float v0 = xv[j * 8 + 2 * p] * rn;
                float v1 = xv[j * 8 + 2 * p + 1] * rn;
                pk4[p] = (unsigned int)f2bf(v0) | ((unsigned int)f2bf(v1) << 16);
            }
            int gs = (cg * 8 + j) ^ (w & 31);
            *(u32x4*)(fnrow + (gs << 4)) = pk4;
        }
    }
    __syncthreads();

    f32x16 acc3[2][2];
#pragma unroll
    for (int i = 0; i < 2; ++i)
#pragma unroll
        for (int j = 0; j < 2; ++j)
#pragma unroll
            for (int r = 0; r < 16; ++r) acc3[i][j][r] = 0.f;

    float regZ[2] = {0.f, 0.f};
    float regM[2] = {-3.0e38f, -3.0e38f};
    const char* fnR0 = FnB + l31 * 1024;
    const char* fnR1 = FnB + (32 + l31) * 1024;

#pragma unroll 1
    for (int kt = 0; kt < 4; ++kt) {
        const char* aG = (const char*)Mn + ((size_t)(kt * 256 + ko * 32 + l31) << 10) + (l5 << 4);
        u32x4 afb[2][4];
        GLOAD16(afb[0][0], aG, 0);
        GLOAD16(afb[0][1], aG, 32);
        GLOAD16(afb[0][2], aG, 64);
        GLOAD16(afb[0][3], aG, 96);
        f32x16 acc1[2];
#pragma unroll
        for (int j = 0; j < 2; ++j)
#pragma unroll
            for (int r = 0; r < 16; ++r) acc1[j][r] = 0.f;
#pragma unroll
        for (int g = 0; g < 8; ++g) {
            if (g < 7) {
#pragma unroll
                for (int s = 0; s < 4; ++s)
                    GLOAD16(afb[(g + 1) & 1][s], aG, ((g + 1) * 4 + s) * 32);
                WAITV(4);
            } else {
                WAITV(0);
            }
#pragma unroll
            for (int s = 0; s < 4; ++s) {
                const int st = g * 4 + s;
                const int gsw = (((st << 1) | l5) ^ l31) << 4;
                short8 b0 = *(const short8*)(fnR0 + gsw);
                short8 b1 = *(const short8*)(fnR1 + gsw);
                short8 av = __builtin_bit_cast(short8, afb[g & 1][s]);
                acc1[0] = mfma32(av, b0, acc1[0]);
                acc1[1] = mfma32(av, b1, acc1[1]);
            }
        }
        const char* aG2a = (const char*)MnT + ((size_t)(cb + l31) << 11) + ((size_t)kt << 9) + (l5 << 4);
        const char* aG2b = aG2a + 65536;
        u32x4 a2b[2][4];
        GLOAD16(a2b[0][0], aG2a, 0);
        GLOAD16(a2b[0][1], aG2b, 0);
        GLOAD16(a2b[0][2], aG2a, 32);
        GLOAD16(a2b[0][3], aG2b, 32);
        unsigned int P32[2][8];
#pragma unroll
        for (int nt = 0; nt < 2; ++nt) {
            float s0 = 0.f, m0 = -3.0e38f;
#pragma unroll
            for (int j = 0; j < 8; ++j) {
                float a0 = acc1[nt][2 * j], a1 = acc1[nt][2 * j + 1];
                m0 = fmaxf(m0, fmaxf(a0, a1));
                float e0 = __expf(a0), e1 = __expf(a1);
                P32[nt][j] = (unsigned int)f2bf(e0) | ((unsigned int)f2bf(e1) << 16);
                s0 += e0 + e1;
            }
            s0 += __shfl_xor(s0, 32);
            m0 = fmaxf(m0, __shfl_xor(m0, 32));
            regZ[nt] += s0;
            regM[nt] = fmaxf(regM[nt], m0);
        }
        char* Pb = PldsB + (kt & 1) * 32768;
#pragma unroll
        for (int nt = 0; nt < 2; ++nt) {
            const int n = nt * 32 + l31;
            char* prow = Pb + n * 512;
#pragma unroll
            for (int jp = 0; jp < 4; ++jp) {
                const int gk = ko * 4 + jp;
                uint2 v;
                v.x = P32[nt][2 * jp];
                v.y = P32[nt][2 * jp + 1];
                *(uint2*)(prow + ((gk ^ (n & 31)) << 4) + 8 * l5) = v;
            }
        }
        LGKM0(); BAR();
#pragma unroll
        for (int g = 0; g < 8; ++g) {
            if (g < 7) {
#pragma unroll
                for (int u = 0; u < 2; ++u) {
                    GLOAD16(a2b[(g + 1) & 1][u * 2 + 0], aG2a, ((g + 1) * 2 + u) * 32);
                    GLOAD16(a2b[(g + 1) & 1][u * 2 + 1], aG2b, ((g + 1) * 2 + u) * 32);
                }
                WAITV(4);
            } else {
                WAITV(0);
            }
#pragma unroll
            for (int u = 0; u < 2; ++u) {
                const int ks = g * 2 + u;
                const int gsw = (((ks << 1) | l5) ^ l31) << 4;
                short8 bp0 = *(const short8*)(Pb + l31 * 512 + gsw);
                short8 bp1 = *(const short8*)(Pb + (32 + l31) * 512 + gsw);
                short8 a0 = __builtin_bit_cast(short8, a2b[g & 1][u * 2 + 0]);
                short8 a1 = __builtin_bit_cast(short8, a2b[g & 1][u * 2 + 1]);
                acc3[0][0] = mfma32(a0, bp0, acc3[0][0]);
                acc3[0][1] = mfma32(a0, bp1, acc3[0][1]);
                acc3[1][0] = mfma32(a1, bp0, acc3[1][0]);
                acc3[1][1] = mfma32(a1, bp1, acc3[1][1]);
            }
        }
    }
    {
        float* pS = (float*)FnB;
        float* pM = (float*)(FnB + 2048);
        if (l5 == 0) {
            pS[ko * 64 + l31] = regZ[0];
            pS[ko * 64 + 32 + l31] = regZ[1];
            pM[ko * 64 + l31] = regM[0];
            pM[ko * 64 + 32 + l31] = regM[1];
        }
        LGKM0(); BAR();
        if (t < 64) {
            float s = 0.f, m = -3.0e38f;
#pragma unroll
            for (int k8 = 0; k8 < 8; ++k8) {
                s += pS[k8 * 64 + t];
                m = fmaxf(m, pM[k8 * 64 + t]);
            }
            float zi = 1.0f / s;
            Zinv[t] = zi;
            match[(size_t)bid * 64 + t] = __expf(m) * zi;
        }
        LGKM0(); BAR();
    }
    const float zi0 = Zinv[l31], zi1 = Zinv[32 + l31];
    float* rbase = recon + (size_t)b * 2097152 + (size_t)h * 64;
#pragma unroll
    for (int ct = 0; ct < 2; ++ct) {
#pragma unroll
        for (int r = 0; r < 16; ++r) {
            const int c = cb + ct * 32 + (r & 3) + 8 * (r >> 2) + 4 * l5;
            float* rp = rbase + (size_t)c * 4096;
            rp[l31] = acc3[ct][0][r] * zi0;
            rp[32 + l31] = acc3[ct][1][r] * zi1;
        }
    }
}

extern "C" void kernel_launch(void* const* d_in, const int* in_sizes, int n_in,
                              void* d_out, int out_size, void* d_ws, size_t ws_size,
                              hipStream_t stream) {
    (void)in_sizes; (void)n_in; (void)out_size;
    if (ws_size < (size_t)2 * 1024 * 1024) return;

    const float* x = (const float*)d_in[0];
    const float* mem = (const float*)d_in[1];
    float* recon = (float*)d_out;
    float* match = recon + (size_t)16 * 512 * 64 * 64;
    char* ws = (char*)d_ws;
    unsigned short* Mn = (unsigned short*)ws;
    unsigned short* MnT = (unsigned short*)(ws + 1048576);

    prep_norm<<<dim3(K_MEM), dim3(256), 0, stream>>>(mem, Mn);
    prep_transpose<<<dim3(128), dim3(256), 0, stream>>>(Mn, MnT);

    const size_t NEED = 207618048ull;  // Mn+MnT+Fn+P+Zp+Mp
    if (ws_size >= NEED) {
        unsigned short* Fn = (unsigned short*)(ws + 2097152);
        unsigned short* P  = (unsigned short*)(ws + 69206016);
        float* Zp = (float*)(ws + 203423744);
        float* Mp = (float*)(ws + 205520896);
        normx_kernel<<<dim3(1024), dim3(512), 0, stream>>>(x, Fn);
        gemm1_kernel<<<dim3(4096), dim3(256), 0, stream>>>(Fn, Mn, P, Zp, Mp);
        gemm2_kernel<<<dim3(2048), dim3(256), 0, stream>>>(P, MnT, Zp, Mp, recon, match);
    } else {
        fused_attn<<<dim3(1024), dim3(512), 0, stream>>>(x, Mn, MnT, recon, match);
    }
}

// Round 16
// 236.571 us; speedup vs baseline: 1.1832x; 1.1832x over previous
//
#include <hip/hip_runtime.h>

// x: [16, 512, 64, 64] fp32, memory: [1024, 512] fp32
// recon: [16, 512, 64, 64] fp32, match: [16, 64, 64] fp32
#define C_DIM 512
#define K_MEM 1024

typedef __attribute__((ext_vector_type(8))) short short8;     // 8 bf16
typedef __attribute__((ext_vector_type(4))) float f32x4;
typedef __attribute__((ext_vector_type(16))) float f32x16;
typedef __attribute__((ext_vector_type(4))) unsigned int u32x4;

#define LGKM0()  asm volatile("s_waitcnt lgkmcnt(0)" ::: "memory")
#define VM0()    asm volatile("s_waitcnt vmcnt(0)" ::: "memory")
#define BAR()    { asm volatile("" ::: "memory"); __builtin_amdgcn_s_barrier(); asm volatile("" ::: "memory"); }

// unsinkable 16B global load (fused-fallback path)
#define GLOAD16(dst, addr, imm) \
    asm volatile("global_load_dwordx4 %0, %1, off offset:%c2" \
                 : "=v"(dst) : "v"(addr), "n"(imm))
#define WAITV(N) do { asm volatile("s_waitcnt vmcnt(%c0)" :: "n"(N) : "memory"); \
                      __builtin_amdgcn_sched_barrier(0); } while (0)

__device__ __forceinline__ unsigned short f2bf(float f) {
    unsigned int u = __builtin_bit_cast(unsigned int, f);
    unsigned int r = (u + 0x7fffu + ((u >> 16) & 1u)) >> 16;  // RNE
    return (unsigned short)r;
}

__device__ __forceinline__ f32x4 mfma16(short8 a, short8 b, f32x4 c) {
    return __builtin_amdgcn_mfma_f32_16x16x32_bf16(a, b, c, 0, 0, 0);
}
__device__ __forceinline__ f32x16 mfma32(short8 a, short8 b, f32x16 c) {
    return __builtin_amdgcn_mfma_f32_32x32x16_bf16(a, b, c, 0, 0, 0);
}

__device__ __forceinline__ void gl_lds16(const void* g, void* l) {
    __builtin_amdgcn_global_load_lds(
        (const __attribute__((address_space(1))) unsigned int*)g,
        (__attribute__((address_space(3))) unsigned int*)l, 16, 0, 0);
}

// ---------------- prep 2: transpose Mn[k][c] -> MnT[c][k] ----------------
__global__ __launch_bounds__(256)
void prep_transpose(const unsigned short* __restrict__ Mn, unsigned short* __restrict__ MnT) {
    __shared__ unsigned short tl[64][72];
    int t = threadIdx.x;
    int bk = blockIdx.x & 15, bc = blockIdx.x >> 4;
    int k0 = bk * 64, c0 = bc * 64;
    {
        int kr = t >> 2, gc = (t & 3) * 16;
        const u32x4* src = reinterpret_cast<const u32x4*>(Mn + (size_t)(k0 + kr) * C_DIM + c0 + gc);
        u32x4 a = src[0], b = src[1];
        *reinterpret_cast<u32x4*>(&tl[kr][gc]) = a;
        *reinterpret_cast<u32x4*>(&tl[kr][gc + 8]) = b;
    }
    __syncthreads();
    {
        int cr = t >> 2, gk = (t & 3) * 16;
        unsigned int ow[8];
#pragma unroll
        for (int j = 0; j < 8; ++j)
            ow[j] = (unsigned int)tl[gk + 2 * j][cr] | ((unsigned int)tl[gk + 2 * j + 1][cr] << 16);
        unsigned int* dst = reinterpret_cast<unsigned int*>(MnT + (size_t)(c0 + cr) * K_MEM + k0 + gk);
#pragma unroll
        for (int j = 0; j < 8; ++j) dst[j] = ow[j];
    }
}

// ---------------- merged: normx (blocks 0..1023) + prep_norm (blocks 1024..2047) ----------------
// normx: L2-normalize feature rows -> Fn[n][c] bf16 (one (b,h) line per block).
// prep_norm: L2-normalize memory row k = bid-1024 -> Mn[k][c] (all 512 threads).
__global__ __launch_bounds__(512)
void normx_kernel(const float* __restrict__ x, unsigned short* __restrict__ Fn,
                  const float* __restrict__ mem, unsigned short* __restrict__ Mn) {
    __shared__ alignas(16) char FnB[65536];   // [64 rows][64 granules 16B], gs = g ^ (w&31)
    __shared__ float normpart[64][9];
    __shared__ float rnormS[64];
    __shared__ float wp[8];
    const int t = threadIdx.x, bid = blockIdx.x;
    const int lane = t & 63, wv = t >> 6;

    if (bid >= 1024) {
        // ---- prep_norm for memory row k; 512 threads, 1 float each ----
        const int k = bid - 1024;
        float v = mem[(size_t)k * C_DIM + t];
        float ss = v * v;
#pragma unroll
        for (int off = 32; off >= 1; off >>= 1) ss += __shfl_xor(ss, off);
        if (lane == 0) wp[wv] = ss;
        __syncthreads();
        float tot = wp[0] + wp[1] + wp[2] + wp[3] + wp[4] + wp[5] + wp[6] + wp[7];
        float rn = 1.0f / fmaxf(sqrtf(tot), 1e-12f);
        Mn[(size_t)k * C_DIM + t] = f2bf(v * rn);
        return;
    }

    // ---- normx: bid = b*64 + h ----
    const int b = bid >> 6, h = bid & 63;
    const int w = lane, cg = wv;
    const float* xp = x + (size_t)b * 2097152 + (size_t)(cg * 64) * 4096 + (size_t)h * 64 + w;
    float xv[64];
#pragma unroll
    for (int i = 0; i < 64; ++i) xv[i] = xp[(size_t)i * 4096];
    float ss = 0.f;
#pragma unroll
    for (int i = 0; i < 64; ++i) ss += xv[i] * xv[i];
    normpart[w][cg] = ss;
    __syncthreads();
    if (t < 64) {
        float s = 0.f;
#pragma unroll
        for (int j = 0; j < 8; ++j) s += normpart[t][j];
        rnormS[t] = 1.0f / fmaxf(sqrtf(s), 1e-12f);
    }
    __syncthreads();
    float rn = rnormS[w];
    char* fnrow = FnB + w * 1024;
#pragma unroll
    for (int j = 0; j < 8; ++j) {
        u32x4 pk4;
#pragma unroll
        for (int p = 0; p < 4; ++p) {
            float v0 = xv[j * 8 + 2 * p] * rn;
            float v1 = xv[j * 8 + 2 * p + 1] * rn;
            pk4[p] = (unsigned int)f2bf(v0) | ((unsigned int)f2bf(v1) << 16);
        }
        int gs = (cg * 8 + j) ^ (w & 31);
        *(u32x4*)(fnrow + (gs << 4)) = pk4;
    }
    __syncthreads();
    const int r = t >> 3;
    char* orow = (char*)(Fn + (size_t)(bid * 64 + r) * C_DIM);
#pragma unroll
    for (int p = 0; p < 8; ++p) {
        int gl = p * 8 + (t & 7);
        u32x4 v = *(const u32x4*)(FnB + r * 1024 + ((gl ^ (r & 31)) << 4));
        *(u32x4*)(orow + gl * 16) = v;
    }
}

// ---------------- shared GEMM staging: 128 rows x 64 cols bf16, source-swizzled ----------------
// LDS linear [128][8 granules of 16B]; LDS[r][g] = G[r][col0 + (g^(r&7))*8 .. +8]. 4 waves.
__device__ __forceinline__ void stage_tile(const char* g0, size_t rowBytes, int col0,
                                           char* lds0, int wv, int lane) {
#pragma unroll
    for (int j = 0; j < 4; ++j) {
        const int chunk = wv * 4 + j;                 // 16 chunks of 8 rows
        const int r = chunk * 8 + (lane >> 3);
        const int gs = (lane & 7) ^ (r & 7);
        const char* src = g0 + (size_t)r * rowBytes + col0 + gs * 16;
        gl_lds16(src, lds0 + chunk * 1024);
    }
}

// frag read: row r (0..127), k-granule gk (0..7) -> 16B
#define FRAG(base, r, gk) (*(const short8*)((base) + (r) * 128 + ((((gk)) ^ ((r) & 7)) << 4)))

// ---------------- GEMM1: S = Fn . Mn^T, fused exp + row partials + P store ----------------
// M=65536, N=1024, K=512. Tile 128x128, BK=64, 4 waves (2m x 2n). grid 4096.
__global__ __launch_bounds__(256, 3)
void gemm1_kernel(const unsigned short* __restrict__ Fn, const unsigned short* __restrict__ Mn,
                  unsigned short* __restrict__ P, float* __restrict__ Zp, float* __restrict__ Mp) {
    __shared__ alignas(16) char LDSU[34816];          // As[16K] + Bs[16K]; epilogue: Pscr[128][272B]
    __shared__ float zS[128][2], zM[128][2];
    char* As = LDSU;
    char* Bs = LDSU + 16384;

    const int wg = (blockIdx.x & 7) * 512 + (blockIdx.x >> 3);  // XCD-chunked
    const int mt = wg >> 3, nt = wg & 7;
    const int m0 = mt * 128, n0 = nt * 128;
    const int t = threadIdx.x, lane = t & 63, wv = t >> 6;
    const int wm = wv >> 1, wn = wv & 1;
    const int l15 = lane & 15, l4 = lane >> 4;

    const char* Ag = (const char*)Fn + (size_t)m0 * 1024;
    const char* Bg = (const char*)Mn + (size_t)n0 * 1024;

    f32x4 acc[4][4];
#pragma unroll
    for (int i = 0; i < 4; ++i)
#pragma unroll
        for (int j = 0; j < 4; ++j) acc[i][j] = (f32x4){0.f, 0.f, 0.f, 0.f};

#pragma unroll 1
    for (int kt = 0; kt < 8; ++kt) {
        stage_tile(Ag, 1024, kt * 128, As, wv, lane);
        stage_tile(Bg, 1024, kt * 128, Bs, wv, lane);
        VM0(); BAR();
#pragma unroll
        for (int ks = 0; ks < 2; ++ks) {
            short8 af[4], bfr[4];
#pragma unroll
            for (int i = 0; i < 4; ++i) {
                af[i]  = FRAG(As, wm * 64 + i * 16 + l15, ks * 4 + l4);
                bfr[i] = FRAG(Bs, wn * 64 + i * 16 + l15, ks * 4 + l4);
            }
#pragma unroll
            for (int mf = 0; mf < 4; ++mf)
#pragma unroll
                for (int nf = 0; nf < 4; ++nf)
                    acc[mf][nf] = mfma16(af[mf], bfr[nf], acc[mf][nf]);
        }
        LGKM0(); BAR();
    }

    // ---- epilogue: exp, row partials (sum & max of exp), P -> global via LDS transpose ----
    float zsum[4][4], zmax[4][4];
#pragma unroll
    for (int mf = 0; mf < 4; ++mf)
#pragma unroll
        for (int r = 0; r < 4; ++r) { zsum[mf][r] = 0.f; zmax[mf][r] = 0.f; }
#pragma unroll
    for (int mf = 0; mf < 4; ++mf)
#pragma unroll
        for (int nf = 0; nf < 4; ++nf)
#pragma unroll
            for (int r = 0; r < 4; ++r) {
                float e = __expf(acc[mf][nf][r]);
                acc[mf][nf][r] = e;                 // reuse acc as exp store
                zsum[mf][r] += e;
                zmax[mf][r] = fmaxf(zmax[mf][r], e);  // max(exp) = exp(max)
            }
#pragma unroll
    for (int off = 1; off < 16; off <<= 1)
#pragma unroll
        for (int mf = 0; mf < 4; ++mf)
#pragma unroll
            for (int r = 0; r < 4; ++r) {
                zsum[mf][r] += __shfl_xor(zsum[mf][r], off);
                zmax[mf][r] = fmaxf(zmax[mf][r], __shfl_xor(zmax[mf][r], off));
            }
    if (l15 == 0) {
#pragma unroll
        for (int mf = 0; mf < 4; ++mf)
#pragma unroll
            for (int r = 0; r < 4; ++r) {
                int row = wm * 64 + mf * 16 + l4 * 4 + r;
                zS[row][wn] = zsum[mf][r];
                zM[row][wn] = zmax[mf][r];
            }
    }
    // P tile -> Pscr (bf16, row stride 272B)
    char* Pscr = LDSU;
#pragma unroll
    for (int mf = 0; mf < 4; ++mf)
#pragma unroll
        for (int nf = 0; nf < 4; ++nf)
#pragma unroll
            for (int r = 0; r < 4; ++r) {
                int row = wm * 64 + mf * 16 + l4 * 4 + r;
                int col = wn * 64 + nf * 16 + l15;
                *(unsigned short*)(Pscr + row * 272 + col * 2) = f2bf(acc[mf][nf][r]);
            }
    LGKM0(); BAR();
    if (t < 128) {
        float zq = zS[t][0] + zS[t][1];
        float mq = fmaxf(zM[t][0], zM[t][1]);
        Zp[(size_t)(m0 + t) * 8 + nt] = zq;
        Mp[(size_t)(m0 + t) * 8 + nt] = mq;
    }
    // coalesced dump of P tile: 4 rows x 256B per wave-instr
#pragma unroll
    for (int p = 0; p < 8; ++p) {
        int r = (t >> 4) + p * 16;
        u32x4 v = *(const u32x4*)(Pscr + r * 272 + (t & 15) * 16);
        *(u32x4*)((char*)P + (size_t)(m0 + r) * 2048 + n0 * 2 + (t & 15) * 16) = v;
    }
}

// ---------------- GEMM2: recon = (P . MnT^T) * Zinv, stats fused, transposed store ----------------
// M=65536(pix), N=512(c), K=1024. Tile 128x128, BK=64, 4 waves. grid 2048.
__global__ __launch_bounds__(256, 3)
void gemm2_kernel(const unsigned short* __restrict__ P, const unsigned short* __restrict__ MnT,
                  const float* __restrict__ Zp, const float* __restrict__ Mp,
                  float* __restrict__ recon, float* __restrict__ match) {
    __shared__ alignas(16) char As[16384];
    __shared__ alignas(16) char Bs[16384];
    __shared__ float zinvS[128];

    const int wg = (blockIdx.x & 7) * 256 + (blockIdx.x >> 3);  // XCD-chunked
    const int mt = wg >> 2, nt = wg & 3;
    const int m0 = mt * 128, n0 = nt * 128;
    const int t = threadIdx.x, lane = t & 63, wv = t >> 6;
    const int wm = wv >> 1, wn = wv & 1;
    const int l15 = lane & 15, l4 = lane >> 4;

    // fused stats: reduce the 8 per-ntile partials; ntile-0 blocks also write match
    if (t < 128) {
        f32x4 a = *(const f32x4*)(Zp + (size_t)(m0 + t) * 8);
        f32x4 b = *(const f32x4*)(Zp + (size_t)(m0 + t) * 8 + 4);
        float s = (a[0] + a[1] + a[2] + a[3]) + (b[0] + b[1] + b[2] + b[3]);
        float zi = 1.0f / s;
        zinvS[t] = zi;
        if (nt == 0) {
            f32x4 c = *(const f32x4*)(Mp + (size_t)(m0 + t) * 8);
            f32x4 d = *(const f32x4*)(Mp + (size_t)(m0 + t) * 8 + 4);
            float m = fmaxf(fmaxf(fmaxf(c[0], c[1]), fmaxf(c[2], c[3])),
                            fmaxf(fmaxf(d[0], d[1]), fmaxf(d[2], d[3])));
            match[m0 + t] = m * zi;
        }
    }

    const char* Ag = (const char*)P + (size_t)m0 * 2048;
    const char* Bg = (const char*)MnT + (size_t)n0 * 2048;

    f32x4 acc[4][4];
#pragma unroll
    for (int i = 0; i < 4; ++i)
#pragma unroll
        for (int j = 0; j < 4; ++j) acc[i][j] = (f32x4){0.f, 0.f, 0.f, 0.f};

#pragma unroll 1
    for (int kt = 0; kt < 16; ++kt) {
        stage_tile(Ag, 2048, kt * 128, As, wv, lane);
        stage_tile(Bg, 2048, kt * 128, Bs, wv, lane);
        VM0(); BAR();
#pragma unroll
        for (int ks = 0; ks < 2; ++ks) {
            short8 af[4], bfr[4];
#pragma unroll
            for (int i = 0; i < 4; ++i) {
                af[i]  = FRAG(As, wm * 64 + i * 16 + l15, ks * 4 + l4);
                bfr[i] = FRAG(Bs, wn * 64 + i * 16 + l15, ks * 4 + l4);
            }
#pragma unroll
            for (int mf = 0; mf < 4; ++mf)
#pragma unroll
                for (int nf = 0; nf < 4; ++nf)
                    acc[mf][nf] = mfma16(af[mf], bfr[nf], acc[mf][nf]);
        }
        LGKM0(); BAR();
    }

    // ---- epilogue: scale by Zinv[pix], store recon[b][c][pix] (f32x4 over pix) ----
    const int b = m0 >> 12;
    const int inb0 = m0 & 4095;
#pragma unroll
    for (int mf = 0; mf < 4; ++mf) {
        f32x4 zv = *(const f32x4*)(&zinvS[wm * 64 + mf * 16 + l4 * 4]);
#pragma unroll
        for (int nf = 0; nf < 4; ++nf) {
            f32x4 v = acc[mf][nf];
            v[0] *= zv[0]; v[1] *= zv[1]; v[2] *= zv[2]; v[3] *= zv[3];
            int c = n0 + wn * 64 + nf * 16 + l15;
            int inb = inb0 + wm * 64 + mf * 16 + l4 * 4;
            *(f32x4*)(recon + (size_t)b * 2097152 + (size_t)c * 4096 + inb) = v;
        }
    }
}

// ---------------- fused fallback (round-6 kernel, used when ws is small) ----------------
__global__ __launch_bounds__(256)
void prep_norm_fb(const float* __restrict__ mem, unsigned short* __restrict__ Mn) {
    int k = blockIdx.x, t = threadIdx.x;
    const float* row = mem + (size_t)k * C_DIM;
    float2 v = *reinterpret_cast<const float2*>(row + 2 * t);
    float ss = v.x * v.x + v.y * v.y;
#pragma unroll
    for (int off = 32; off >= 1; off >>= 1) ss += __shfl_xor(ss, off);
    __shared__ float wp[4];
    if ((t & 63) == 0) wp[t >> 6] = ss;
    __syncthreads();
    float tot = wp[0] + wp[1] + wp[2] + wp[3];
    float rn = 1.0f / fmaxf(sqrtf(tot), 1e-12f);
    unsigned int pk = (unsigned int)f2bf(v.x * rn) | ((unsigned int)f2bf(v.y * rn) << 16);
    *reinterpret_cast<unsigned int*>(Mn + (size_t)k * C_DIM + 2 * t) = pk;
}

__global__ __launch_bounds__(512)
__attribute__((amdgpu_waves_per_eu(2, 2)))
void fused_attn(const float* __restrict__ x,
                const unsigned short* __restrict__ Mn,
                const unsigned short* __restrict__ MnT,
                float* __restrict__ recon,
                float* __restrict__ match) {
    __shared__ alignas(16) char FnB[65536];
    __shared__ alignas(16) char PldsB[2 * 32768];
    __shared__ float Zinv[64], rnormS[64];

    const int t = threadIdx.x;
    const int bid = blockIdx.x;
    const int b = bid >> 6, h = bid & 63;
    const int lane = t & 63, wv = t >> 6;
    const int l31 = lane & 31, l5 = lane >> 5;
    const int ko = wv;
    const int cb = wv * 64;

    {
        float* normpart = (float*)PldsB;
        const int w = lane, cg = wv;
        const float* xp = x + (size_t)b * 2097152 + (size_t)(cg * 64) * 4096 + (size_t)h * 64 + w;
        float xv[64];
#pragma unroll
        for (int i = 0; i < 64; ++i) xv[i] = xp[(size_t)i * 4096];
        float ss = 0.f;
#pragma unroll
        for (int i = 0; i < 64; ++i) ss += xv[i] * xv[i];
        normpart[w * 9 + cg] = ss;
        __syncthreads();
        if (t < 64) {
            float s = 0.f;
#pragma unroll
            for (int j = 0; j < 8; ++j) s += normpart[t * 9 + j];
            rnormS[t] = 1.0f / fmaxf(sqrtf(s), 1e-12f);
        }
        __syncthreads();
        float rn = rnormS[w];
        char* fnrow = FnB + w * 1024;
#pragma unroll
        for (int j = 0; j < 8; ++j) {
            u32x4 pk4;
#pragma unroll
            for (int p = 0; p < 4; ++p) {
                float v0 = xv[j * 8 + 2 * p] * rn;
                float v1 = xv[j * 8 + 2 * p + 1] * rn;
                pk4[p] = (unsigned int)f2bf(v0) | ((unsigned int)f2bf(v1) << 16);
            }
            int gs = (cg * 8 + j) ^ (w & 31);
            *(u32x4*)(fnrow + (gs << 4)) = pk4;
        }
    }
    __syncthreads();

    f32x16 acc3[2][2];
#pragma unroll
    for (int i = 0; i < 2; ++i)
#pragma unroll
        for (int j = 0; j < 2; ++j)
#pragma unroll
            for (int r = 0; r < 16; ++r) acc3[i][j][r] = 0.f;

    float regZ[2] = {0.f, 0.f};
    float regM[2] = {-3.0e38f, -3.0e38f};
    const char* fnR0 = FnB + l31 * 1024;
    const char* fnR1 = FnB + (32 + l31) * 1024;

#pragma unroll 1
    for (int kt = 0; kt < 4; ++kt) {
        const char* aG = (const char*)Mn + ((size_t)(kt * 256 + ko * 32 + l31) << 10) + (l5 << 4);
        u32x4 afb[2][4];
        GLOAD16(afb[0][0], aG, 0);
        GLOAD16(afb[0][1], aG, 32);
        GLOAD16(afb[0][2], aG, 64);
        GLOAD16(afb[0][3], aG, 96);
        f32x16 acc1[2];
#pragma unroll
        for (int j = 0; j < 2; ++j)
#pragma unroll
            for (int r = 0; r < 16; ++r) acc1[j][r] = 0.f;
#pragma unroll
        for (int g = 0; g < 8; ++g) {
            if (g < 7) {
#pragma unroll
                for (int s = 0; s < 4; ++s)
                    GLOAD16(afb[(g + 1) & 1][s], aG, ((g + 1) * 4 + s) * 32);
                WAITV(4);
            } else {
                WAITV(0);
            }
#pragma unroll
            for (int s = 0; s < 4; ++s) {
                const int st = g * 4 + s;
                const int gsw = (((st << 1) | l5) ^ l31) << 4;
                short8 b0 = *(const short8*)(fnR0 + gsw);
                short8 b1 = *(const short8*)(fnR1 + gsw);
                short8 av = __builtin_bit_cast(short8, afb[g & 1][s]);
                acc1[0] = mfma32(av, b0, acc1[0]);
                acc1[1] = mfma32(av, b1, acc1[1]);
            }
        }
        const char* aG2a = (const char*)MnT + ((size_t)(cb + l31) << 11) + ((size_t)kt << 9) + (l5 << 4);
        const char* aG2b = aG2a + 65536;
        u32x4 a2b[2][4];
        GLOAD16(a2b[0][0], aG2a, 0);
        GLOAD16(a2b[0][1], aG2b, 0);
        GLOAD16(a2b[0][2], aG2a, 32);
        GLOAD16(a2b[0][3], aG2b, 32);
        unsigned int P32[2][8];
#pragma unroll
        for (int nt = 0; nt < 2; ++nt) {
            float s0 = 0.f, m0 = -3.0e38f;
#pragma unroll
            for (int j = 0; j < 8; ++j) {
                float a0 = acc1[nt][2 * j], a1 = acc1[nt][2 * j + 1];
                m0 = fmaxf(m0, fmaxf(a0, a1));
                float e0 = __expf(a0), e1 = __expf(a1);
                P32[nt][j] = (unsigned int)f2bf(e0) | ((unsigned int)f2bf(e1) << 16);
                s0 += e0 + e1;
            }
            s0 += __shfl_xor(s0, 32);
            m0 = fmaxf(m0, __shfl_xor(m0, 32));
            regZ[nt] += s0;
            regM[nt] = fmaxf(regM[nt], m0);
        }
        char* Pb = PldsB + (kt & 1) * 32768;
#pragma unroll
        for (int nt = 0; nt < 2; ++nt) {
            const int n = nt * 32 + l31;
            char* prow = Pb + n * 512;
#pragma unroll
            for (int jp = 0; jp < 4; ++jp) {
                const int gk = ko * 4 + jp;
                uint2 v;
                v.x = P32[nt][2 * jp];
                v.y = P32[nt][2 * jp + 1];
                *(uint2*)(prow + ((gk ^ (n & 31)) << 4) + 8 * l5) = v;
            }
        }
        LGKM0(); BAR();
#pragma unroll
        for (int g = 0; g < 8; ++g) {
            if (g < 7) {
#pragma unroll
                for (int u = 0; u < 2; ++u) {
                    GLOAD16(a2b[(g + 1) & 1][u * 2 + 0], aG2a, ((g + 1) * 2 + u) * 32);
                    GLOAD16(a2b[(g + 1) & 1][u * 2 + 1], aG2b, ((g + 1) * 2 + u) * 32);
                }
                WAITV(4);
            } else {
                WAITV(0);
            }
#pragma unroll
            for (int u = 0; u < 2; ++u) {
                const int ks = g * 2 + u;
                const int gsw = (((ks << 1) | l5) ^ l31) << 4;
                short8 bp0 = *(const short8*)(Pb + l31 * 512 + gsw);
                short8 bp1 = *(const short8*)(Pb + (32 + l31) * 512 + gsw);
                short8 a0 = __builtin_bit_cast(short8, a2b[g & 1][u * 2 + 0]);
                short8 a1 = __builtin_bit_cast(short8, a2b[g & 1][u * 2 + 1]);
                acc3[0][0] = mfma32(a0, bp0, acc3[0][0]);
                acc3[0][1] = mfma32(a0, bp1, acc3[0][1]);
                acc3[1][0] = mfma32(a1, bp0, acc3[1][0]);
                acc3[1][1] = mfma32(a1, bp1, acc3[1][1]);
            }
        }
    }
    {
        float* pS = (float*)FnB;
        float* pM = (float*)(FnB + 2048);
        if (l5 == 0) {
            pS[ko * 64 + l31] = regZ[0];
            pS[ko * 64 + 32 + l31] = regZ[1];
            pM[ko * 64 + l31] = regM[0];
            pM[ko * 64 + 32 + l31] = regM[1];
        }
        LGKM0(); BAR();
        if (t < 64) {
            float s = 0.f, m = -3.0e38f;
#pragma unroll
            for (int k8 = 0; k8 < 8; ++k8) {
                s += pS[k8 * 64 + t];
                m = fmaxf(m, pM[k8 * 64 + t]);
            }
            float zi = 1.0f / s;
            Zinv[t] = zi;
            match[(size_t)bid * 64 + t] = __expf(m) * zi;
        }
        LGKM0(); BAR();
    }
    const float zi0 = Zinv[l31], zi1 = Zinv[32 + l31];
    float* rbase = recon + (size_t)b * 2097152 + (size_t)h * 64;
#pragma unroll
    for (int ct = 0; ct < 2; ++ct) {
#pragma unroll
        for (int r = 0; r < 16; ++r) {
            const int c = cb + ct * 32 + (r & 3) + 8 * (r >> 2) + 4 * l5;
            float* rp = rbase + (size_t)c * 4096;
            rp[l31] = acc3[ct][0][r] * zi0;
            rp[32 + l31] = acc3[ct][1][r] * zi1;
        }
    }
}

extern "C" void kernel_launch(void* const* d_in, const int* in_sizes, int n_in,
                              void* d_out, int out_size, void* d_ws, size_t ws_size,
                              hipStream_t stream) {
    (void)in_sizes; (void)n_in; (void)out_size;
    if (ws_size < (size_t)2 * 1024 * 1024) return;

    const float* x = (const float*)d_in[0];
    const float* mem = (const float*)d_in[1];
    float* recon = (float*)d_out;
    float* match = recon + (size_t)16 * 512 * 64 * 64;
    char* ws = (char*)d_ws;
    unsigned short* Mn = (unsigned short*)ws;
    unsigned short* MnT = (unsigned short*)(ws + 1048576);

    const size_t NEED = 207618048ull;  // Mn+MnT+Fn+P+Zp+Mp
    if (ws_size >= NEED) {
        unsigned short* Fn = (unsigned short*)(ws + 2097152);
        unsigned short* P  = (unsigned short*)(ws + 69206016);
        float* Zp = (float*)(ws + 203423744);
        float* Mp = (float*)(ws + 205520896);
        normx_kernel<<<dim3(2048), dim3(512), 0, stream>>>(x, Fn, mem, Mn);  // + fused prep_norm
        prep_transpose<<<dim3(128), dim3(256), 0, stream>>>(Mn, MnT);
        gemm1_kernel<<<dim3(4096), dim3(256), 0, stream>>>(Fn, Mn, P, Zp, Mp);
        gemm2_kernel<<<dim3(2048), dim3(256), 0, stream>>>(P, MnT, Zp, Mp, recon, match);
    } else {
        prep_norm_fb<<<dim3(K_MEM), dim3(256), 0, stream>>>(mem, Mn);
        prep_transpose<<<dim3(128), dim3(256), 0, stream>>>(Mn, MnT);
        fused_attn<<<dim3(1024), dim3(512), 0, stream>>>(x, Mn, MnT, recon, match);
    }
}